// Round 10
// baseline (612.506 us; speedup 1.0000x reference)
//
#include <hip/hip_runtime.h>
#include <hip/hip_bf16.h>
#include <cstdint>
#include <cstddef>

// MultiScaleQuantizer: z (256,32,16,16) fp32, embed (4096,32) fp32.
// Outputs concat (fp32): f_hat (2097152), idx@pn=1..16 (87296), loss (1).
//
// r26 = r25 + chunk-min worklists for the big scales (pn=8,16):
//  phaseA already computes each point's min over the block's 256-code chunk
//  (post-butterfly mn) -- now it also STORES it (chunkmin[y*N+n]).
//  A point needs chunk y rescanned iff chunkmin_y(p) <= globalmin(p)+MARGIN;
//  phaseA/phaseB compute the bitwise-identical bf16 metric (same MFMA, same
//  operands), so this filter is exact: the candidate set collected equals
//  r16/r25's phaseB set, hence identical winners/tie-breaks after the
//  exact-fp32 rescue. Expected qualifying chunks/pt ~1.05 of 16 -> phaseB
//  work /15. compact kernel (ballot-aggregated) builds per-chunk lists;
//  vq_phaseB_wl gathers its points' af frags (16B L2 gathers, r24-verified),
//  stages code windows exactly as classic phaseB, same gate/drill/rescue.
//  Partial groups pad with a duplicated point (atomicMin idempotent).
//  Small scales (pn=1,2,4) keep the classic phaseB.

#define B_   256
#define V_   4096
#define NTOT 2097152   // 256*32*16*16
#define WIN  128       // codebook window staged in LDS
#define CAP  512       // classic phaseB candidate capacity
#define CAPW 1024      // worklist phaseB candidate capacity
#define MARGIN_ 1.0f

using bf16x8 = __attribute__((ext_vector_type(8))) short;
using f32x4  = __attribute__((ext_vector_type(4))) float;

__device__ inline short f2bf(float f) {
  __hip_bfloat16 h = __float2bfloat16(f);
  return *reinterpret_cast<short*>(&h);
}
__device__ inline unsigned encf(float f) {        // monotone fp32 -> u32
  unsigned u = __float_as_uint(f);
  return (u & 0x80000000u) ? ~u : (u | 0x80000000u);
}
__device__ inline float decf(unsigned u) {
  unsigned b = (u & 0x80000000u) ? (u ^ 0x80000000u) : ~u;
  return __uint_as_float(b);
}
__device__ inline int keyidx(unsigned long long k) {  // decode + clamp (safety)
  int i = (int)(unsigned)(k & 0xffffffffull);
  return min(max(i, 0), V_ - 1);
}
__device__ inline float min3f(float a, float b, float c) {
  float d;
  asm("v_min3_f32 %0, %1, %2, %3" : "=v"(d) : "v"(a), "v"(b), "v"(c));
  return d;
}

// ---- setup: f_rest=z, zrow/zrowb@pn1, ebf, se, tables, inits ----
// block = one (b,c) plane; blockIdx.x = b*32+c
__global__ __launch_bounds__(256) void setup_kernel(
    const float* __restrict__ z, const float* __restrict__ embed,
    float* __restrict__ f_rest, float* __restrict__ zrow,
    short* __restrict__ zrowb, short* __restrict__ ebf,
    float* __restrict__ se, float* __restrict__ tables,
    float* __restrict__ loss_slots, unsigned long long* __restrict__ keys0,
    unsigned int* __restrict__ smin0, int* __restrict__ cnt0)
{
  const int tid = threadIdx.x;
  const int t = blockIdx.x * 256 + tid;
  float v = z[t];
  f_rest[t] = v;

  __shared__ float sm[256];
  sm[tid] = v;
  __syncthreads();
  if (tid == 0) {
    float s = 0.f;
    for (int i = 0; i < 256; ++i) s += sm[i];   // ref's linear i,j order
    int c = blockIdx.x & 31, b = blockIdx.x >> 5;
    float val = s * (1.0f / 256.0f);
    zrow[(size_t)b * 32 + c] = val;             // row-major [n][32] (tiny @pn1)
    zrowb[(size_t)b * 32 + c] = f2bf(-val);     // negated bf16 A-frag source
  }

  if (blockIdx.x < 16) {                        // se + ebf: 16*256 codes
    int code = blockIdx.x * 256 + tid;
    float s = 0.f;
#pragma unroll
    for (int c = 0; c < 32; ++c) {
      float e = embed[(size_t)code * 32 + c];
      ebf[(size_t)code * 32 + c] = f2bf(e);
      s += e * e;                                // sequential like ref
    }
    se[code] = s;
  } else if (blockIdx.x == 16) {
    if (tid < 64) {
      int pn_i = tid >> 4;          // 0..3 -> pn = 1,2,4,8
      int o    = tid & 15;
      int pn   = 1 << pn_i;
      double scale = (double)pn / 16.0;
      double x  = (o + 0.5) * scale - 0.5;
      double x0 = floor(x);
      double tf = x - x0;
      float row[8];
#pragma unroll
      for (int h = 0; h < 8; ++h) row[h] = 0.f;
      const double A = -0.75;
#pragma unroll
      for (int off = -1; off <= 2; ++off) {
        double s = fabs(tf - (double)off);
        double cub;
        if (s <= 1.0)      cub = ((A + 2.0) * s - (A + 3.0)) * s * s + 1.0;
        else if (s < 2.0)  cub = (((s - 5.0) * s + 8.0) * s - 4.0) * A;
        else               cub = 0.0;
        int idx = (int)x0 + off;
        idx = min(max(idx, 0), pn - 1);
        row[idx] = (float)((double)row[idx] + cub);  // numpy f32 += f64
      }
#pragma unroll
      for (int h = 0; h < 8; ++h) tables[pn_i * 128 + o * 8 + h] = row[h];
    }
  } else if (blockIdx.x == 17) {
    keys0[tid] = ~0ull;                          // pn=1: N=256
    smin0[tid] = 0xFFFFFFFFu;
  } else if (blockIdx.x == 18) {
    if (tid < 32) cnt0[tid] = 0;                 // worklist counters (2 scales)
  } else if (blockIdx.x >= 20 && blockIdx.x < 60) {
    loss_slots[(blockIdx.x - 20) * 256 + tid] = 0.f;   // 40*256 = 10240 zeros
  }
}

// ---------------- phase A: MFMA scan -> per-point min of s=se/2-dot ----------
// block 256 = 4 waves x 32 points (2 frags/wave); grid.x = N/128,
// grid.y = v-chunks. Optionally stores per-chunk per-point min (worklists).
__global__ __launch_bounds__(256) void vq_phaseA_kernel(
    const short* __restrict__ zrowb, const short* __restrict__ ebf,
    const float* __restrict__ se, unsigned int* __restrict__ smin,
    int vchunk, unsigned int* __restrict__ chunkmin, int N)
{
  __shared__ __align__(16) short elds[WIN * 40]; // padded stride 80B rows
  __shared__ float selds[WIN];

  const int tid = threadIdx.x;
  const int lane = tid & 63, wave = tid >> 6;
  const int col = lane & 15, quad = lane >> 4;
  const int nw = blockIdx.x * 128 + wave * 32;
  const int vbase = blockIdx.y * vchunk;

  // A-frags: one coalesced 16B load each from pre-negated bf16 z rows
  bf16x8 af[2];
#pragma unroll
  for (int f = 0; f < 2; ++f)
    af[f] = *(const bf16x8*)(zrowb + (size_t)(nw + f * 16 + col) * 32 + quad * 8);

  float mn[2][4];
#pragma unroll
  for (int f = 0; f < 2; ++f)
#pragma unroll
    for (int r = 0; r < 4; ++r) mn[f][r] = 3.4e38f;

  for (int w0 = 0; w0 < vchunk; w0 += WIN) {
    __syncthreads();
    {
      // 128 rows x 2 threads; each thread stores 2 bf16x8 = full 32-short row
      int row = tid >> 1, half = tid & 1;
      const bf16x8* src = (const bf16x8*)(ebf + (size_t)(vbase + w0 + row) * 32);
      bf16x8* dst = (bf16x8*)(elds + row * 40);
      dst[half * 2]     = src[half * 2];
      dst[half * 2 + 1] = src[half * 2 + 1];
      if (tid < WIN) selds[tid] = 0.5f * se[vbase + w0 + tid];  // *0.5 exact
    }
    __syncthreads();
    for (int vv = 0; vv < WIN; vv += 16) {
      bf16x8 bf = *(const bf16x8*)(elds + (vv + col) * 40 + quad * 8);
      float sevh = selds[vv + col];
      f32x4 cin = {sevh, sevh, sevh, sevh};       // D = se/2 + (-z)*e
#pragma unroll
      for (int f = 0; f < 2; ++f) {
        f32x4 d = __builtin_amdgcn_mfma_f32_16x16x32_bf16(af[f], bf, cin, 0, 0, 0);
#pragma unroll
        for (int r = 0; r < 4; ++r) mn[f][r] = fminf(mn[f][r], d[r]);
      }
    }
  }
  // cross-col min via shuffle butterfly
#pragma unroll
  for (int f = 0; f < 2; ++f)
#pragma unroll
    for (int r = 0; r < 4; ++r) {
      float m = mn[f][r];
      m = fminf(m, __shfl_xor(m, 1, 64));
      m = fminf(m, __shfl_xor(m, 2, 64));
      m = fminf(m, __shfl_xor(m, 4, 64));
      m = fminf(m, __shfl_xor(m, 8, 64));
      mn[f][r] = m;
    }
  if (col == 0) {
#pragma unroll
    for (int f = 0; f < 2; ++f)
#pragma unroll
      for (int r = 0; r < 4; ++r) {
        unsigned e = encf(mn[f][r]);
        int n = nw + f * 16 + quad * 4 + r;
        atomicMin(&smin[n], e);
        if (chunkmin) chunkmin[(size_t)blockIdx.y * N + n] = e;
      }
  }
}

// -------- classic phase B (pn=1,2,4): full re-scan with gate + rescue -------
__global__ __launch_bounds__(256) void vq_phaseB_kernel(
    const short* __restrict__ zrowb, const short* __restrict__ ebf,
    const float* __restrict__ se, const unsigned int* __restrict__ smin,
    const float* __restrict__ zrow, const float* __restrict__ embed,
    unsigned long long* __restrict__ keys, int vchunk, int nmax)
{
  __shared__ __align__(16) short elds[WIN * 40];
  __shared__ float selds[WIN];
  __shared__ unsigned long long clist[CAP];
  __shared__ int ccnt;

  const int tid = threadIdx.x;
  const int lane = tid & 63, wave = tid >> 6;
  const int col = lane & 15, quad = lane >> 4;
  const int nw = blockIdx.x * 128 + wave * 32;
  const int vbase = blockIdx.y * vchunk;

  if (tid == 0) ccnt = 0;
  __syncthreads();

  bf16x8 af[2];
#pragma unroll
  for (int f = 0; f < 2; ++f)
    af[f] = *(const bf16x8*)(zrowb + (size_t)(nw + f * 16 + col) * 32 + quad * 8);

  float thr[2][4];
#pragma unroll
  for (int f = 0; f < 2; ++f)
#pragma unroll
    for (int r = 0; r < 4; ++r)
      thr[f][r] = decf(smin[nw + f * 16 + quad * 4 + r]) + MARGIN_;
  float tmax = fmaxf(
      fmaxf(fmaxf(thr[0][0], thr[0][1]), fmaxf(thr[0][2], thr[0][3])),
      fmaxf(fmaxf(thr[1][0], thr[1][1]), fmaxf(thr[1][2], thr[1][3])));

  for (int w0 = 0; w0 < vchunk; w0 += WIN) {
    __syncthreads();
    {
      int row = tid >> 1, half = tid & 1;       // full-row staging (see A)
      const bf16x8* src = (const bf16x8*)(ebf + (size_t)(vbase + w0 + row) * 32);
      bf16x8* dst = (bf16x8*)(elds + row * 40);
      dst[half * 2]     = src[half * 2];
      dst[half * 2 + 1] = src[half * 2 + 1];
      if (tid < WIN) selds[tid] = 0.5f * se[vbase + w0 + tid];
    }
    __syncthreads();
    for (int vv = 0; vv < WIN; vv += 16) {
      bf16x8 bf = *(const bf16x8*)(elds + (vv + col) * 40 + quad * 8);
      float sevh = selds[vv + col];
      f32x4 cin = {sevh, sevh, sevh, sevh};
      f32x4 dd[2];
      dd[0] = __builtin_amdgcn_mfma_f32_16x16x32_bf16(af[0], bf, cin, 0, 0, 0);
      dd[1] = __builtin_amdgcn_mfma_f32_16x16x32_bf16(af[1], bf, cin, 0, 0, 0);
      float a = min3f(dd[0][0], dd[0][1], dd[0][2]);
      float b = min3f(dd[0][3], dd[1][0], dd[1][1]);
      float c = min3f(dd[1][2], dd[1][3], a);
      if (fminf(b, c) <= tmax) {
#pragma unroll
        for (int f = 0; f < 2; ++f) {
#pragma unroll
          for (int r = 0; r < 4; ++r) {
            if (dd[f][r] <= thr[f][r]) {
              int n = nw + f * 16 + quad * 4 + r;
              int v = vbase + w0 + vv + col;
              int slot = atomicAdd(&ccnt, 1);
              if (slot < CAP) {
                clist[slot] =
                    ((unsigned long long)(unsigned)n << 32) | (unsigned)v;
              } else {
                const float* zp = zrow + (size_t)n * 32;
                const float* ep = embed + (size_t)v * 32;
                float dot = 0.f, sz = 0.f;
#pragma unroll 1
                for (int i = 0; i < 32; ++i) {
                  float zc = zp[i];
                  dot = fmaf(zc, ep[i], dot);
                  sz  = fmaf(zc, zc, sz);
                }
                float d = fmaf(-2.0f, dot, sz) + se[v];
                unsigned long long key =
                    ((unsigned long long)encf(d) << 32) | (unsigned)v;
                atomicMin(&keys[n], key);
              }
            }
          }
        }
      }
    }
  }

  __syncthreads();
  int tot = min(ccnt, CAP);
  for (int j = tid; j < tot; j += 256) {
    unsigned long long cv = clist[j];
    int n = min((int)(cv >> 32), nmax - 1);
    int v = min((int)(cv & 0xffffffffull), V_ - 1);
    const float* zp = zrow + (size_t)n * 32;
    const float* ep = embed + (size_t)v * 32;
    float dot = 0.f, sz = 0.f;
#pragma unroll
    for (int i = 0; i < 32; ++i) {
      float zc = zp[i];
      dot = fmaf(zc, ep[i], dot);
      sz  = fmaf(zc, zc, sz);
    }
    float d = fmaf(-2.0f, dot, sz) + se[v];
    unsigned long long key =
        ((unsigned long long)encf(d) << 32) | (unsigned)v;
    atomicMin(&keys[n], key);
  }
}

// ---- compact: per point, emit n into lists of chunks whose chunkmin
// qualifies (chunkmin <= globalmin + MARGIN). Exact filter (same bf16 metric).
__global__ __launch_bounds__(256) void compact_kernel(
    const unsigned int* __restrict__ smin,
    const unsigned int* __restrict__ chunkmin, int N, int nvc,
    int* __restrict__ cnt, int* __restrict__ list)
{
  const int n = blockIdx.x * 256 + threadIdx.x;
  const int lane = threadIdx.x & 63;
  const float thr = decf(smin[n]) + MARGIN_;
  for (int y = 0; y < nvc; ++y) {
    bool q = decf(chunkmin[(size_t)y * N + n]) <= thr;
    unsigned long long m = __ballot(q);
    int base = 0;
    if (lane == 0 && m) base = atomicAdd(&cnt[y], (int)__popcll(m));
    base = __shfl(base, 0, 64);
    if (q) {
      int pos = base + (int)__popcll(m & ((1ull << lane) - 1ull));
      list[(size_t)y * N + pos] = n;
    }
  }
}

// -------- worklist phase B (pn=8,16): rescan only qualifying chunks --------
// grid (32, NVC): block (x,y) strides over chunk y's point list in groups
// of 128. Same staging/gate/drill/rescue as classic; points gathered.
__global__ __launch_bounds__(256) void vq_phaseB_wl_kernel(
    const short* __restrict__ zrowb, const short* __restrict__ ebf,
    const float* __restrict__ se, const unsigned int* __restrict__ smin,
    const float* __restrict__ zrow, const float* __restrict__ embed,
    unsigned long long* __restrict__ keys, int vchunk, int N,
    const int* __restrict__ cnt, const int* __restrict__ list)
{
  __shared__ __align__(16) short elds[WIN * 40];
  __shared__ float selds[WIN];
  __shared__ unsigned long long clist[CAPW];
  __shared__ int ptls[128];
  __shared__ int ccnt;

  const int tid = threadIdx.x;
  const int lane = tid & 63, wave = tid >> 6;
  const int col = lane & 15, quad = lane >> 4;
  const int y = blockIdx.y;
  const int vbase = y * vchunk;
  const int total = cnt[y];

  if (tid == 0) ccnt = 0;

  for (int base = blockIdx.x * 128; base < total; base += gridDim.x * 128) {
    __syncthreads();                     // protect ptls/elds from prior group
    if (tid < 128)
      ptls[tid] = list[(size_t)y * N + min(base + tid, total - 1)];
    __syncthreads();

    bf16x8 af[2];
    float thr[2][4];
#pragma unroll
    for (int f = 0; f < 2; ++f) {
      int pm = ptls[wave * 32 + f * 16 + col];
      af[f] = *(const bf16x8*)(zrowb + (size_t)pm * 32 + quad * 8);
#pragma unroll
      for (int r = 0; r < 4; ++r)
        thr[f][r] = decf(smin[ptls[wave * 32 + f * 16 + quad * 4 + r]]) + MARGIN_;
    }
    float tmax = fmaxf(
        fmaxf(fmaxf(thr[0][0], thr[0][1]), fmaxf(thr[0][2], thr[0][3])),
        fmaxf(fmaxf(thr[1][0], thr[1][1]), fmaxf(thr[1][2], thr[1][3])));

    for (int w0 = 0; w0 < vchunk; w0 += WIN) {
      __syncthreads();
      {
        int row = tid >> 1, half = tid & 1;
        const bf16x8* src = (const bf16x8*)(ebf + (size_t)(vbase + w0 + row) * 32);
        bf16x8* dst = (bf16x8*)(elds + row * 40);
        dst[half * 2]     = src[half * 2];
        dst[half * 2 + 1] = src[half * 2 + 1];
        if (tid < WIN) selds[tid] = 0.5f * se[vbase + w0 + tid];
      }
      __syncthreads();
      for (int vv = 0; vv < WIN; vv += 16) {
        bf16x8 bf = *(const bf16x8*)(elds + (vv + col) * 40 + quad * 8);
        float sevh = selds[vv + col];
        f32x4 cin = {sevh, sevh, sevh, sevh};
        f32x4 dd[2];
        dd[0] = __builtin_amdgcn_mfma_f32_16x16x32_bf16(af[0], bf, cin, 0, 0, 0);
        dd[1] = __builtin_amdgcn_mfma_f32_16x16x32_bf16(af[1], bf, cin, 0, 0, 0);
        float a = min3f(dd[0][0], dd[0][1], dd[0][2]);
        float b = min3f(dd[0][3], dd[1][0], dd[1][1]);
        float c = min3f(dd[1][2], dd[1][3], a);
        if (fminf(b, c) <= tmax) {
#pragma unroll
          for (int f = 0; f < 2; ++f) {
#pragma unroll
            for (int r = 0; r < 4; ++r) {
              if (dd[f][r] <= thr[f][r]) {
                int n = ptls[wave * 32 + f * 16 + quad * 4 + r];
                int v = vbase + w0 + vv + col;
                int slot = atomicAdd(&ccnt, 1);
                if (slot < CAPW) {
                  clist[slot] =
                      ((unsigned long long)(unsigned)n << 32) | (unsigned)v;
                } else {
                  const float* zp = zrow + (size_t)n * 32;
                  const float* ep = embed + (size_t)v * 32;
                  float dot = 0.f, sz = 0.f;
#pragma unroll 1
                  for (int i = 0; i < 32; ++i) {
                    float zc = zp[i];
                    dot = fmaf(zc, ep[i], dot);
                    sz  = fmaf(zc, zc, sz);
                  }
                  float d = fmaf(-2.0f, dot, sz) + se[v];
                  unsigned long long key =
                      ((unsigned long long)encf(d) << 32) | (unsigned)v;
                  atomicMin(&keys[n], key);
                }
              }
            }
          }
        }
      }
    }
  }

  __syncthreads();
  int tot = min(ccnt, CAPW);
  for (int j = tid; j < tot; j += 256) {
    unsigned long long cv = clist[j];
    int n = min((int)(cv >> 32), N - 1);
    int v = min((int)(cv & 0xffffffffull), V_ - 1);
    const float* zp = zrow + (size_t)n * 32;
    const float* ep = embed + (size_t)v * 32;
    float dot = 0.f, sz = 0.f;
#pragma unroll
    for (int i = 0; i < 32; ++i) {
      float zc = zp[i];
      dot = fmaf(zc, ep[i], dot);
      sz  = fmaf(zc, zc, sz);
    }
    float d = fmaf(-2.0f, dot, sz) + se[v];
    unsigned long long key =
        ((unsigned long long)encf(d) << 32) | (unsigned)v;
    atomicMin(&keys[n], key);
  }
}

// ---- upsample + f_rest update + loss + idx out + next-scale prep ----
// block = one (b,c) plane; blockIdx.x = b*32+c; tid = o*16+p
// zavg written COL-major (coalesced); transpose kernel makes row-major.
__global__ __launch_bounds__(256) void up_update_kernel(
    const float* __restrict__ embed, const unsigned long long* __restrict__ keys,
    const float* __restrict__ tbl, float* __restrict__ f_rest, int pn,
    float* __restrict__ zcol,
    unsigned long long* __restrict__ keys_nb, unsigned int* __restrict__ smin_nb,
    int pn_next, int n_next,
    float* __restrict__ idx_out, float* __restrict__ loss_slot)
{
  __shared__ float sm[256];
  __shared__ float sm_e[64];
  const int tid = threadIdx.x;
  const int t = blockIdx.x * 256 + tid;
  const int p = tid & 15, o = tid >> 4;
  const int c = blockIdx.x & 31, b = blockIdx.x >> 5;
  const int pn2 = pn * pn;

  float pre = f_rest[t];
  sm[tid] = pre;
  if (tid < pn2) {
    int idx = keyidx(keys[b * pn2 + tid]);
    if (c == 0) idx_out[b * pn2 + tid] = (float)idx;
    sm_e[tid] = embed[(size_t)idx * 32 + c];
  }
  __syncthreads();

  // loss partial: recompute zavg from pre-update plane
  float lsum = 0.f;
  if (tid < pn2) {
    int k = 16 / pn;
    int ph = tid / pn, pw = tid - ph * pn;
    float s = 0.f;
    for (int i = 0; i < k; ++i)
      for (int j = 0; j < k; ++j)
        s += sm[(ph * k + i) * 16 + (pw * k + j)];
    float zavg = s * (1.0f / (k * k));
    float d = sm_e[tid] - zavg;
    lsum = d * d;
  }
#pragma unroll
  for (int off = 32; off > 0; off >>= 1) lsum += __shfl_down(lsum, off, 64);
  if ((tid & 63) == 0)
    atomicAdd(loss_slot + ((blockIdx.x & 127) << 4), lsum);

  // bicubic upsample (ref: h-einsum first, then w)
  const float* Wo = tbl + o * 8;
  const float* Wp = tbl + p * 8;
  float acc = 0.f;
  for (int w = 0; w < pn; ++w) {
    float inner = 0.f;
    for (int h = 0; h < pn; ++h)
      inner = fmaf(Wo[h], sm_e[h * pn + w], inner);
    acc = fmaf(Wp[w], inner, acc);
  }
  float nr = pre - acc;
  f_rest[t] = nr;

  __syncthreads();
  sm[tid] = nr;
  __syncthreads();
  const int pnn2 = pn_next * pn_next;
  if (tid < pnn2) {
    int ph = tid / pn_next, pw = tid - ph * pn_next;
    int k = 16 / pn_next;
    float s = 0.f;
    for (int i = 0; i < k; ++i)
      for (int j = 0; j < k; ++j)
        s += sm[(ph * k + i) * 16 + (pw * k + j)];
    float zavg = s * (1.0f / (k * k));
    // col-major: consecutive tid -> consecutive addresses (coalesced)
    zcol[(size_t)c * 65536 + b * pnn2 + tid] = zavg;
  }
  if (t < n_next) {                // reset ping-pong buffers for next scale
    keys_nb[t] = ~0ull;
    smin_nb[t] = 0xFFFFFFFFu;
  }
}

// ---- transpose zcol [32][65536-stride] -> zrow [n][32] + zrowb bf16(-v) ----
__global__ __launch_bounds__(256) void zpack_transpose_kernel(
    const float* __restrict__ zcol, float* __restrict__ zrow,
    short* __restrict__ zrowb)
{
  __shared__ float tile[64][33];
  const int tid = threadIdx.x;
  const int nb = blockIdx.x * 64;
  const int pt = tid & 63, cg = tid >> 6;    // point, channel-group (0..3)
#pragma unroll
  for (int it = 0; it < 8; ++it) {
    int c = it * 4 + cg;
    tile[pt][c] = zcol[(size_t)c * 65536 + nb + pt];
  }
  __syncthreads();
  const int p = tid >> 2, q = tid & 3;       // row, quarter (8 floats)
  float v[8];
#pragma unroll
  for (int k = 0; k < 8; ++k) v[k] = tile[p][q * 8 + k];
  float* op = zrow + (size_t)(nb + p) * 32 + q * 8;
  f32x4 lo = {v[0], v[1], v[2], v[3]};
  f32x4 hi = {v[4], v[5], v[6], v[7]};
  *(f32x4*)op = lo;
  *(f32x4*)(op + 4) = hi;
  bf16x8 bv;
#pragma unroll
  for (int k = 0; k < 8; ++k) bv[k] = f2bf(-v[k]);
  *(bf16x8*)(zrowb + (size_t)(nb + p) * 32 + q * 8) = bv;
}

// -- final scale (pn=16): out = (z - f_rest) + embed[idx], idx out, loss --
__global__ __launch_bounds__(256) void final_add_kernel(
    const float* __restrict__ z, const float* __restrict__ f_rest,
    const float* __restrict__ embed, const unsigned long long* __restrict__ keys,
    float* __restrict__ f_hat, float* __restrict__ idx_out,
    float* __restrict__ loss_slot)
{
  const int tid = threadIdx.x;
  const int t = blockIdx.x * 256 + tid;
  const int c = blockIdx.x & 31, b = blockIdx.x >> 5;
  const int n = b * 256 + tid;
  int idx = keyidx(keys[n]);
  if (c == 0) idx_out[n] = (float)idx;
  float e = embed[(size_t)idx * 32 + c];
  float fr = f_rest[t];
  f_hat[t] = (z[t] - fr) + e;   // f_hat = sum of zq (err ~1e-6)
  float d = e - fr;             // fr == zavg at pn=16 bit-exactly
  float lsum = d * d;
#pragma unroll
  for (int off = 32; off > 0; off >>= 1) lsum += __shfl_down(lsum, off, 64);
  if ((tid & 63) == 0)
    atomicAdd(loss_slot + ((blockIdx.x & 127) << 4), lsum);
}

// ------------- final loss reduce: 5 scales x 128 padded slots -------------
__global__ __launch_bounds__(128) void loss_final_kernel(
    const float* __restrict__ loss_slots, float* __restrict__ out_loss)
{
  __shared__ float lred[2];
  const int tid = threadIdx.x;   // 128 threads = 2 waves
  const float numel[5] = {8192.f, 32768.f, 131072.f, 524288.f, 2097152.f};
  float tot = 0.f;
  for (int s = 0; s < 5; ++s) {
    float x = loss_slots[s * 2048 + tid * 16];
#pragma unroll
    for (int off = 32; off > 0; off >>= 1) x += __shfl_down(x, off, 64);
    if ((tid & 63) == 0) lred[tid >> 6] = x;
    __syncthreads();
    if (tid == 0) {
      float m = (lred[0] + lred[1]) / numel[s];
      tot += 0.25f * m + m;        // beta*mean + mean
    }
    __syncthreads();
  }
  if (tid == 0) out_loss[0] = tot / 5.f;
}

// =========================== host launcher ===========================
extern "C" void kernel_launch(void* const* d_in, const int* in_sizes, int n_in,
                              void* d_out, int out_size, void* d_ws, size_t ws_size,
                              hipStream_t stream)
{
  const float* z     = (const float*)d_in[0];
  const float* embed = (const float*)d_in[1];
  float* out = (float*)d_out;
  float* ws  = (float*)d_ws;

  // ws layout (float slots), total ~7666208 floats ~= 29.3 MiB
  float* f_rest  = ws;                                   // 2097152
  float* zrow    = ws + 2097152;                         // [65536][32] f32
  short* zrowb   = (short*)(ws + 4194304);               // [65536][32] bf16(-z)
  short* ebf     = (short*)(ws + 5242880);               // 131072 shorts
  float* se      = ws + 5308416;                         // 4096
  unsigned int* smin0 = (unsigned int*)(ws + 5312512);   // 65536 u32
  unsigned int* smin1 = (unsigned int*)(ws + 5378048);   // 16384 u32
  unsigned long long* keys0 = (unsigned long long*)(ws + 5394432); // 65536 u64
  unsigned long long* keys1 = (unsigned long long*)(ws + 5525504); // 16384 u64
  float* loss_slots = ws + 5558272;                      // 5*128*16 = 10240
  float* tables     = ws + 5568512;                      // 512
  int*   cnt0       = (int*)(ws + 5569024);              // 32 ints
  unsigned int* chunkmin = (unsigned int*)(ws + 5569056); // 16*65536 u32
  int*   list       = (int*)(ws + 6617632);              // 16*65536 int

  // zcol scratch = f_hat region of d_out; final_add overwrites it last.
  float* zcol = out;

  unsigned long long* keysb[2] = {keys0, keys1};
  unsigned int*       sminb[2] = {smin0, smin1};

  setup_kernel<<<NTOT / 256, 256, 0, stream>>>(z, embed, f_rest, zrow, zrowb,
                                               ebf, se, tables, loss_slots,
                                               keys0, smin0, cnt0);

  const int PN[5]  = {1, 2, 4, 8, 16};
  const int NVC[5] = {32, 32, 32, 16, 16};  // v-chunks; vchunk multiple of WIN
  int idx_off = NTOT;
  for (int i = 0; i < 5; ++i) {
    int pn = PN[i];
    int N  = B_ * pn * pn;
    int vchunk = V_ / NVC[i];
    unsigned long long* kb = keysb[i & 1];
    unsigned int*       sb = sminb[i & 1];
    dim3 g(N / 128, NVC[i]);                  // 2-frag waves: 128 points/block
    vq_phaseA_kernel<<<g, 256, 0, stream>>>(zrowb, ebf, se, sb, vchunk,
                                            (i >= 3) ? chunkmin : nullptr, N);
    if (i < 3) {
      vq_phaseB_kernel<<<g, 256, 0, stream>>>(zrowb, ebf, se, sb, zrow, embed,
                                              kb, vchunk, N);
    } else {
      int* cnt = cnt0 + (i - 3) * 16;
      compact_kernel<<<N / 256, 256, 0, stream>>>(sb, chunkmin, N, NVC[i],
                                                  cnt, list);
      dim3 gw(32, NVC[i]);
      vq_phaseB_wl_kernel<<<gw, 256, 0, stream>>>(zrowb, ebf, se, sb, zrow,
                                                  embed, kb, vchunk, N,
                                                  cnt, list);
    }
    if (i < 4) {
      int pnn = PN[i + 1];
      int n_next = B_ * pnn * pnn;
      up_update_kernel<<<NTOT / 256, 256, 0, stream>>>(
          embed, kb, tables + i * 128, f_rest, pn,
          zcol, keysb[(i + 1) & 1], sminb[(i + 1) & 1],
          pnn, n_next, out + idx_off, loss_slots + i * 2048);
      zpack_transpose_kernel<<<n_next / 64, 256, 0, stream>>>(zcol, zrow,
                                                              zrowb);
    } else {
      final_add_kernel<<<NTOT / 256, 256, 0, stream>>>(
          z, f_rest, embed, kb, out, out + idx_off, loss_slots + 4 * 2048);
    }
    idx_off += N;
  }
  loss_final_kernel<<<1, 128, 0, stream>>>(loss_slots, out + 2184448);
}